// Round 19
// baseline (379.624 us; speedup 1.0000x reference)
//
#include <hip/hip_runtime.h>

// Output layout (floats): [0]=loss, [1..8388608]=quantized BCHW,
// [8388609]=perplexity, [8388610..]=encodings (N x K)
#define QUANT_OFF 1
#define PERP_OFF 8388609
#define ENC_OFF  8388610

// ws: [0,2048)    counts u32[512]
//     [2048,2052) ticket u32
//     [4096,8192) lpart f32[1024]
//     [8192,73728) w2 bf16[512*64]  (-2W)

typedef __attribute__((ext_vector_type(8))) short bf16x8;
typedef __attribute__((ext_vector_type(2))) float f32x2;
typedef __attribute__((ext_vector_type(4))) float f32x4;

__device__ __forceinline__ unsigned short f2bf(float f) {
  unsigned int u = __float_as_uint(f);
  u += 0x7fffu + ((u >> 16) & 1u);
  return (unsigned short)(u >> 16);
}

// 512 blocks x 64 thr: sw2, bf16(-2W) pack, counts + ticket zeroing
__global__ void vq_prep(const float* __restrict__ W, float* __restrict__ sw2,
                        unsigned short* __restrict__ w2,
                        unsigned int* __restrict__ counts,
                        unsigned int* __restrict__ ticket) {
  int k = blockIdx.x;
  int d = threadIdx.x;
  float wd = W[k * 64 + d];
  w2[k * 64 + d] = f2bf(-2.0f * wd);
  float s = wd * wd;
  #pragma unroll
  for (int off = 32; off; off >>= 1) s += __shfl_down(s, off, 64);
  if (d == 0) {
    sw2[k] = s; counts[k] = 0u;
    if (k == 0) *ticket = 0u;
  }
}

// R18 core; two overhead removals:
//  (1) pre-barrier1 role swap: FILLER waves stage W/sw2 into LDS while
//      compute waves load x (concurrent instead of serial, fillers not idle)
//  (2) finalizer fused via last-block ticket (saves a dispatch + gap)
// 512 thr = 8 waves (4 compute + 4 filler), 128 pts/block, grid 1024
// -> two staggered rounds, 2 blocks/CU.
__global__ __launch_bounds__(512, 4) void vq_mega(
    const float* __restrict__ x, const unsigned short* __restrict__ w2,
    const float* __restrict__ sw2g, const float* __restrict__ W,
    unsigned int* __restrict__ counts, float* __restrict__ lpart,
    unsigned int* __restrict__ ticket, float* __restrict__ out) {
  __shared__ unsigned short wlds[512 * 72];  // 73728 B, padded rows
  __shared__ float sw2s[512];
  __shared__ unsigned int hcnt[512];
  __shared__ int   sbi[128];
  __shared__ float lred[4];
  __shared__ int   islast;

  int tid  = threadIdx.x;
  int lane = tid & 63;
  int wv   = tid >> 6;          // 0..7
  int nb0  = blockIdx.x << 7;   // block's first point (128/block)
  int b    = nb0 >> 12;         // never crosses a batch
  int hw0b = nb0 & 4095;
  int rl   = lane & 15;
  int g    = lane >> 4;

  hcnt[tid] = 0u;

  bf16x8 xfA0, xfA1, xfB0, xfB1;
  float cnA = 0.0f, cnB = 0.0f;

  if (wv < 4) {
    // ---- compute waves: x loads + frag pack (concurrent with staging) ----
    int n0  = nb0 + (wv << 5);          // wave's 32 points
    int hw0 = n0 & 4095;
    const float* xb = x + b * 262144 + hw0;
    #pragma unroll
    for (int e = 0; e < 8; ++e) {
      int d0 = (g * 8 + e) * 4096, d1 = (32 + g * 8 + e) * 4096;
      float a0 = xb[d0 + rl],      a1 = xb[d1 + rl];
      float b0 = xb[d0 + 16 + rl], b1 = xb[d1 + 16 + rl];
      cnA = fmaf(a0, a0, fmaf(a1, a1, cnA));
      cnB = fmaf(b0, b0, fmaf(b1, b1, cnB));
      xfA0[e] = f2bf(a0); xfA1[e] = f2bf(a1);
      xfB0[e] = f2bf(b0); xfB1[e] = f2bf(b1);
    }
    cnA += __shfl_xor(cnA, 16); cnA += __shfl_xor(cnA, 32);
    cnB += __shfl_xor(cnB, 16); cnB += __shfl_xor(cnB, 32);
  } else {
    // ---- filler waves: stage bf16 (-2W) + sw2 into LDS (pre-fill) ----
    int ct = ((wv - 4) << 6) + lane;    // 0..255
    #pragma unroll
    for (int i = 0; i < 16; ++i) {
      int u = (i << 8) + ct;            // 4096 units of 8 bf16
      int r = u >> 3, c = u & 7;
      *(bf16x8*)&wlds[r * 72 + c * 8] = *(const bf16x8*)&w2[u * 8];
    }
    sw2s[ct] = sw2g[ct];
    sw2s[ct + 256] = sw2g[ct + 256];
  }
  __syncthreads();   // barrier1: staging visible; fill window opens

  if (wv < 4) {
    // ---- MFMA argmin over 32 code-tiles (pure LDS/VALU/MFMA window) ----
    float bestA = __uint_as_float(0x7f7fffffu);
    float bestB = __uint_as_float(0x7f7fffffu);
    int rowoff = rl * 72 + g * 8;
    #pragma unroll 8
    for (int t = 0; t < 32; ++t) {
      f32x4 sv = *(const f32x4*)&sw2s[t * 16 + g * 4];
      int tb = t * 1152 + rowoff;
      bf16x8 a0 = *(const bf16x8*)&wlds[tb];
      bf16x8 a1 = *(const bf16x8*)&wlds[tb + 32];
      f32x4 accA = sv, accB = sv;
      accA = __builtin_amdgcn_mfma_f32_16x16x32_bf16(a0, xfA0, accA, 0, 0, 0);
      accA = __builtin_amdgcn_mfma_f32_16x16x32_bf16(a1, xfA1, accA, 0, 0, 0);
      accB = __builtin_amdgcn_mfma_f32_16x16x32_bf16(a0, xfB0, accB, 0, 0, 0);
      accB = __builtin_amdgcn_mfma_f32_16x16x32_bf16(a1, xfB1, accB, 0, 0, 0);
      #pragma unroll
      for (int j = 0; j < 4; ++j) {
        unsigned int ki = (unsigned int)(t * 16 + g * 4 + j);
        bestA = fminf(bestA, __uint_as_float((__float_as_uint(accA[j]) & ~511u) | ki));
        bestB = fminf(bestB, __uint_as_float((__float_as_uint(accB[j]) & ~511u) | ki));
      }
    }
    bestA = fminf(bestA, __shfl_xor(bestA, 16));
    bestA = fminf(bestA, __shfl_xor(bestA, 32));
    bestB = fminf(bestB, __shfl_xor(bestB, 16));
    bestB = fminf(bestB, __shfl_xor(bestB, 32));
    int biA = __float_as_uint(bestA) & 511;
    int biB = __float_as_uint(bestB) & 511;
    float scoreA = __uint_as_float(__float_as_uint(bestA) & ~511u);
    float scoreB = __uint_as_float(__float_as_uint(bestB) & ~511u);

    if (lane < 16) {
      sbi[(wv << 5) + rl] = biA;
      atomicAdd(&hcnt[biA], 1u);
    } else if (lane < 32) {
      sbi[(wv << 5) + 16 + rl] = biB;
      atomicAdd(&hcnt[biB], 1u);
    }
    float dl = (cnA + scoreA) + (cnB + scoreB);   // 4 copies/point in wave
    #pragma unroll
    for (int off = 1; off < 64; off <<= 1) dl += __shfl_xor(dl, off);
    if (lane == 0) lred[wv] = dl * 0.25f;
  } else {
    // ---- filler waves: 64KB of enc zeros each, f32x2 (8B-aligned) ----
    int fw = wv - 4;                    // 0..3 -> rows [fw*32, fw*32+32)
    f32x2* dst = (f32x2*)(out + ENC_OFF)
               + (((long long)(nb0 + (fw << 5))) << 8);   // row = 256 f32x2
    f32x2 z2; z2.x = 0.f; z2.y = 0.f;
    #pragma unroll 8
    for (int i = 0; i < 128; ++i)
      dst[(i << 6) + lane] = z2;        // 8192 f32x2 = 64KB
  }
  __syncthreads();   // barrier2: zeros drained -> visible; sbi ready

  // ---- tail: the 128 single 1.0s ----
  if (tid < 128)
    out[ENC_OFF + ((long long)(nb0 + tid) << 9) + sbi[tid]] = 1.0f;

  // ---- quantized: all 8 waves, coalesced (256B/instr/wave) ----
  {
    int p = tid & 127, qr = tid >> 7;            // 4 channel-quarters
    int bip = sbi[p];
    const f32x4* wr4 = (const f32x4*)(W + (bip << 6) + (qr << 4));
    float* qp = out + QUANT_OFF + b * 262144 + ((qr << 4) * 4096) + hw0b + p;
    #pragma unroll
    for (int cq = 0; cq < 4; ++cq) {
      f32x4 wv4 = wr4[cq];
      qp[(cq * 4 + 0) * 4096] = wv4[0];
      qp[(cq * 4 + 1) * 4096] = wv4[1];
      qp[(cq * 4 + 2) * 4096] = wv4[2];
      qp[(cq * 4 + 3) * 4096] = wv4[3];
    }
  }

  // ---- bookkeeping flush ----
  {
    unsigned int hv = hcnt[tid];
    if (hv) atomicAdd(&counts[tid], hv);
  }
  if (tid == 0) lpart[blockIdx.x] = (lred[0] + lred[1]) + (lred[2] + lred[3]);

  // ---- last-block fused finalizer ----
  __threadfence();
  __syncthreads();
  if (tid == 0) islast = (atomicAdd(ticket, 1u) == 1023u) ? 1 : 0;
  __syncthreads();
  if (islast) {
    __shared__ float red[8], red2[8];
    int k = tid;  // 512 threads
    float pr = (float)counts[k] * (1.0f / 131072.0f);
    float s = pr * logf(pr + 1e-10f);
    float l = lpart[k] + lpart[k + 512];
    #pragma unroll
    for (int off = 32; off; off >>= 1) {
      s += __shfl_down(s, off, 64);
      l += __shfl_down(l, off, 64);
    }
    if ((k & 63) == 0) { red[k >> 6] = s; red2[k >> 6] = l; }
    __syncthreads();
    if (k == 0) {
      float H = 0.0f, L = 0.0f;
      #pragma unroll
      for (int i = 0; i < 8; ++i) { H += red[i]; L += red2[i]; }
      out[PERP_OFF] = expf(-H);
      out[0] = 1.25f * L * (1.0f / 8388608.0f);
    }
  }
}

extern "C" void kernel_launch(void* const* d_in, const int* in_sizes, int n_in,
                              void* d_out, int out_size, void* d_ws, size_t ws_size,
                              hipStream_t stream) {
  (void)in_sizes; (void)n_in; (void)out_size; (void)ws_size;
  const float* x = (const float*)d_in[0];
  const float* W = (const float*)d_in[1];
  float* out = (float*)d_out;

  char* ws = (char*)d_ws;
  unsigned int* counts = (unsigned int*)ws;
  unsigned int* ticket = (unsigned int*)(ws + 2048);
  float* sw2           = (float*)(ws + 2052);   // 512 f32 fits in [2052,4096)? no:
  // keep sw2 in its own region to stay 4B-aligned and roomy:
  float* lpart         = (float*)(ws + 4096);
  unsigned short* w2   = (unsigned short*)(ws + 8192);
  float* sw2r          = (float*)(ws + 73728);  // sw2 f32[512] after w2

  vq_prep<<<512, 64, 0, stream>>>(W, sw2r, w2, counts, ticket);
  vq_mega<<<1024, 512, 0, stream>>>(x, w2, sw2r, W, counts, lpart, ticket, out);
  (void)sw2;
}

// Round 20
// 75.728 us; speedup vs baseline: 5.0130x; 5.0130x over previous
//
#include <hip/hip_runtime.h>

// Output layout (floats): [0]=loss, [1..8388608]=quantized BCHW,
// [8388609]=perplexity, [8388610..]=encodings (N x K)
#define QUANT_OFF 1
#define PERP_OFF 8388609
#define ENC_OFF  8388610

// ws: [0,2048)    counts u32[512]
//     [2048,4096) sw2 f32[512]
//     [4096,8192) lpart f32[1024]
//     [8192,73728) w2 bf16[512*64]  (-2W)

typedef __attribute__((ext_vector_type(8))) short bf16x8;
typedef __attribute__((ext_vector_type(2))) float f32x2;
typedef __attribute__((ext_vector_type(4))) float f32x4;

__device__ __forceinline__ unsigned short f2bf(float f) {
  unsigned int u = __float_as_uint(f);
  u += 0x7fffu + ((u >> 16) & 1u);
  return (unsigned short)(u >> 16);
}

// 512 blocks x 64 thr: sw2, bf16(-2W) pack, counts zeroing
__global__ void vq_prep(const float* __restrict__ W, float* __restrict__ sw2,
                        unsigned short* __restrict__ w2,
                        unsigned int* __restrict__ counts) {
  int k = blockIdx.x;
  int d = threadIdx.x;
  float wd = W[k * 64 + d];
  w2[k * 64 + d] = f2bf(-2.0f * wd);
  float s = wd * wd;
  #pragma unroll
  for (int off = 32; off; off >>= 1) s += __shfl_down(s, off, 64);
  if (d == 0) { sw2[k] = s; counts[k] = 0u; }
}

// R18 champion structure (77.1us), reverted verbatim after R19's regression
// (fused finalizer + staging role-swap destroyed codegen: VGPR 52, spills,
// 1M LDS bank conflicts). 512 thr = 8 waves (4 compute + 4 filler),
// 128 points/block, grid 1024 -> two staggered rounds, 2 blocks/CU.
// Fill window is PURE: compute waves touch only LDS/VALU/MFMA there.
__global__ __launch_bounds__(512, 4) void vq_mega(
    const float* __restrict__ x, const unsigned short* __restrict__ w2,
    const float* __restrict__ sw2g, const float* __restrict__ W,
    unsigned int* __restrict__ counts, float* __restrict__ lpart,
    float* __restrict__ out) {
  __shared__ unsigned short wlds[512 * 72];  // 73728 B, padded rows
  __shared__ float sw2s[512];
  __shared__ unsigned int hcnt[512];
  __shared__ int   sbi[128];
  __shared__ float lred[4];

  int tid  = threadIdx.x;
  int lane = tid & 63;
  int wv   = tid >> 6;          // 0..7
  int nb0  = blockIdx.x << 7;   // block's first point (128/block)
  int b    = nb0 >> 12;         // never crosses a batch
  int hw0b = nb0 & 4095;
  int rl   = lane & 15;
  int g    = lane >> 4;

  hcnt[tid] = 0u;

  bf16x8 xfA0, xfA1, xfB0, xfB1;
  float cnA = 0.0f, cnB = 0.0f;

  if (wv < 4) {
    // ---- compute waves: x frags + W staging (all reads BEFORE the fill)
    int n0  = nb0 + (wv << 5);          // wave's 32 points
    int hw0 = n0 & 4095;
    const float* xb = x + b * 262144 + hw0;
    #pragma unroll
    for (int e = 0; e < 8; ++e) {
      int d0 = (g * 8 + e) * 4096, d1 = (32 + g * 8 + e) * 4096;
      float a0 = xb[d0 + rl],      a1 = xb[d1 + rl];
      float b0 = xb[d0 + 16 + rl], b1 = xb[d1 + 16 + rl];
      cnA = fmaf(a0, a0, fmaf(a1, a1, cnA));
      cnB = fmaf(b0, b0, fmaf(b1, b1, cnB));
      xfA0[e] = f2bf(a0); xfA1[e] = f2bf(a1);
      xfB0[e] = f2bf(b0); xfB1[e] = f2bf(b1);
    }
    cnA += __shfl_xor(cnA, 16); cnA += __shfl_xor(cnA, 32);
    cnB += __shfl_xor(cnB, 16); cnB += __shfl_xor(cnB, 32);

    // stage bf16 (-2W) into padded LDS: 16 units per thread, 256 threads
    int ct = (wv << 6) + lane;          // 0..255
    #pragma unroll
    for (int i = 0; i < 16; ++i) {
      int u = (i << 8) + ct;            // 4096 units of 8 bf16
      int r = u >> 3, c = u & 7;
      *(bf16x8*)&wlds[r * 72 + c * 8] = *(const bf16x8*)&w2[u * 8];
    }
    sw2s[ct] = sw2g[ct];
    sw2s[ct + 256] = sw2g[ct + 256];
  }
  __syncthreads();   // barrier1: staging done; fill window opens

  if (wv < 4) {
    // ---- MFMA argmin over 32 code-tiles (pure LDS/VALU/MFMA window) ----
    float bestA = __uint_as_float(0x7f7fffffu);
    float bestB = __uint_as_float(0x7f7fffffu);
    int rowoff = rl * 72 + g * 8;
    #pragma unroll 8
    for (int t = 0; t < 32; ++t) {
      f32x4 sv = *(const f32x4*)&sw2s[t * 16 + g * 4];
      int tb = t * 1152 + rowoff;
      bf16x8 a0 = *(const bf16x8*)&wlds[tb];
      bf16x8 a1 = *(const bf16x8*)&wlds[tb + 32];
      f32x4 accA = sv, accB = sv;
      accA = __builtin_amdgcn_mfma_f32_16x16x32_bf16(a0, xfA0, accA, 0, 0, 0);
      accA = __builtin_amdgcn_mfma_f32_16x16x32_bf16(a1, xfA1, accA, 0, 0, 0);
      accB = __builtin_amdgcn_mfma_f32_16x16x32_bf16(a0, xfB0, accB, 0, 0, 0);
      accB = __builtin_amdgcn_mfma_f32_16x16x32_bf16(a1, xfB1, accB, 0, 0, 0);
      #pragma unroll
      for (int j = 0; j < 4; ++j) {
        unsigned int ki = (unsigned int)(t * 16 + g * 4 + j);
        bestA = fminf(bestA, __uint_as_float((__float_as_uint(accA[j]) & ~511u) | ki));
        bestB = fminf(bestB, __uint_as_float((__float_as_uint(accB[j]) & ~511u) | ki));
      }
    }
    bestA = fminf(bestA, __shfl_xor(bestA, 16));
    bestA = fminf(bestA, __shfl_xor(bestA, 32));
    bestB = fminf(bestB, __shfl_xor(bestB, 16));
    bestB = fminf(bestB, __shfl_xor(bestB, 32));
    int biA = __float_as_uint(bestA) & 511;
    int biB = __float_as_uint(bestB) & 511;
    float scoreA = __uint_as_float(__float_as_uint(bestA) & ~511u);
    float scoreB = __uint_as_float(__float_as_uint(bestB) & ~511u);

    if (lane < 16) {
      sbi[(wv << 5) + rl] = biA;
      atomicAdd(&hcnt[biA], 1u);
    } else if (lane < 32) {
      sbi[(wv << 5) + 16 + rl] = biB;
      atomicAdd(&hcnt[biB], 1u);
    }
    float dl = (cnA + scoreA) + (cnB + scoreB);   // 4 copies/point in wave
    #pragma unroll
    for (int off = 1; off < 64; off <<= 1) dl += __shfl_xor(dl, off);
    if (lane == 0) lred[wv] = dl * 0.25f;
  } else {
    // ---- filler waves: 64KB of enc zeros each, f32x2 (8B-aligned) ----
    int fw = wv - 4;                    // 0..3 -> rows [fw*32, fw*32+32)
    f32x2* dst = (f32x2*)(out + ENC_OFF)
               + (((long long)(nb0 + (fw << 5))) << 8);   // row = 256 f32x2
    f32x2 z2; z2.x = 0.f; z2.y = 0.f;
    #pragma unroll 8
    for (int i = 0; i < 128; ++i)
      dst[(i << 6) + lane] = z2;        // 8192 f32x2 = 64KB
  }
  __syncthreads();   // barrier2: zeros drained -> visible; sbi ready

  // ---- tail: the 128 single 1.0s ----
  if (tid < 128)
    out[ENC_OFF + ((long long)(nb0 + tid) << 9) + sbi[tid]] = 1.0f;

  // ---- quantized: all 8 waves, coalesced (256B/instr/wave) ----
  {
    int p = tid & 127, qr = tid >> 7;            // 4 channel-quarters
    int bip = sbi[p];
    const f32x4* wr4 = (const f32x4*)(W + (bip << 6) + (qr << 4));
    float* qp = out + QUANT_OFF + b * 262144 + ((qr << 4) * 4096) + hw0b + p;
    #pragma unroll
    for (int cq = 0; cq < 4; ++cq) {
      f32x4 wv4 = wr4[cq];
      qp[(cq * 4 + 0) * 4096] = wv4[0];
      qp[(cq * 4 + 1) * 4096] = wv4[1];
      qp[(cq * 4 + 2) * 4096] = wv4[2];
      qp[(cq * 4 + 3) * 4096] = wv4[3];
    }
  }

  // ---- bookkeeping flush ----
  {
    unsigned int hv = hcnt[tid];
    if (hv) atomicAdd(&counts[tid], hv);
  }
  if (tid == 0) {
    float s = (lred[0] + lred[1]) + (lred[2] + lred[3]);
    lpart[blockIdx.x] = s;
  }
}

// Tiny finalizer: perplexity from counts, loss from 1024 block partials.
__global__ void vq_final(const unsigned int* __restrict__ counts,
                         const float* __restrict__ lpart,
                         float* __restrict__ out) {
  __shared__ float red[8], red2[8];
  int k = threadIdx.x;  // 512 threads
  float pr = (float)counts[k] * (1.0f / 131072.0f);
  float s = pr * logf(pr + 1e-10f);
  float l = lpart[k] + lpart[k + 512];
  #pragma unroll
  for (int off = 32; off; off >>= 1) {
    s += __shfl_down(s, off, 64);
    l += __shfl_down(l, off, 64);
  }
  if ((k & 63) == 0) { red[k >> 6] = s; red2[k >> 6] = l; }
  __syncthreads();
  if (k == 0) {
    float H = 0.0f, L = 0.0f;
    #pragma unroll
    for (int i = 0; i < 8; ++i) { H += red[i]; L += red2[i]; }
    out[PERP_OFF] = expf(-H);
    out[0] = 1.25f * L * (1.0f / 8388608.0f);
  }
}

extern "C" void kernel_launch(void* const* d_in, const int* in_sizes, int n_in,
                              void* d_out, int out_size, void* d_ws, size_t ws_size,
                              hipStream_t stream) {
  (void)in_sizes; (void)n_in; (void)out_size; (void)ws_size;
  const float* x = (const float*)d_in[0];
  const float* W = (const float*)d_in[1];
  float* out = (float*)d_out;

  char* ws = (char*)d_ws;
  unsigned int* counts = (unsigned int*)ws;
  float* sw2           = (float*)(ws + 2048);
  float* lpart         = (float*)(ws + 4096);
  unsigned short* w2   = (unsigned short*)(ws + 8192);

  vq_prep<<<512, 64, 0, stream>>>(W, sw2, w2, counts);
  vq_mega<<<1024, 512, 0, stream>>>(x, w2, sw2, W, counts, lpart, out);
  vq_final<<<1, 512, 0, stream>>>(counts, lpart, out);
}